// Round 1
// 244.522 us; speedup vs baseline: 1.0058x; 1.0058x over previous
//
#include <hip/hip_runtime.h>
#include <hip/hip_bf16.h>

#define NS 512
#define NV 32000
#define NB 16
#define NT 128

#ifndef __has_builtin
#define __has_builtin(x) 0
#endif

typedef int v8i __attribute__((ext_vector_type(8)));
typedef float v4f __attribute__((ext_vector_type(4)));

// ---------------------------------------------------------------------------
// e4m3fn (OCP) encode, x >= 0.
// ---------------------------------------------------------------------------
__device__ inline unsigned enc_e4m3(float x) {
    x = fminf(x, 448.0f);
    unsigned u = __float_as_uint(x);
    if (x < 0.015625f) {
        return (unsigned)(int)rintf(x * 512.0f);
    }
    unsigned u2 = u + 0x7FFFFu + ((u >> 20) & 1u);
    return (((u2 >> 23) - 120u) << 3) | ((u2 >> 20) & 7u);
}

__device__ inline unsigned pack4_e4m3(float a, float b, float c, float d) {
#if __has_builtin(__builtin_amdgcn_cvt_pk_fp8_f32)
    int v = __builtin_amdgcn_cvt_pk_fp8_f32(a, b, 0, false);
    v = __builtin_amdgcn_cvt_pk_fp8_f32(c, d, v, true);
    return (unsigned)v;
#else
    return enc_e4m3(a) | (enc_e4m3(b) << 8) | (enc_e4m3(c) << 16) | (enc_e4m3(d) << 24);
#endif
}

// DPP all-lane butterfly reduce within each row of 16 lanes.
#define DPPMAX(x, ctrl) \
    x = fmaxf(x, __int_as_float(__builtin_amdgcn_mov_dpp(__float_as_int(x), ctrl, 0xF, 0xF, true)))
#define DPPADD(x, ctrl) \
    x = x + __int_as_float(__builtin_amdgcn_mov_dpp(__float_as_int(x), ctrl, 0xF, 0xF, true))

#define UMX(a, b) ((a) > (b) ? (a) : (b))

// ---------------------------------------------------------------------------
// K1a: per-state logZ over vocab + emission gather, COALESCED store to
// em_lin_T[s][j] = exp(em[s][ids_j]) / Z_s * 2^-18.
// ---------------------------------------------------------------------------
__global__ __launch_bounds__(256) void k_emtok_T(
    const float* __restrict__ em, const int* __restrict__ ids,
    float* __restrict__ em_lin_T)
{
    const int s   = blockIdx.x;
    const int tid = threadIdx.x;
    const float* row = em + (size_t)s * NV;

    int idv[8];
#pragma unroll
    for (int k = 0; k < 8; ++k) idv[k] = ids[tid + 256 * k];
    float g[8];
#pragma unroll
    for (int k = 0; k < 8; ++k) g[k] = row[idv[k]];

    float sum = 0.f;
    const float4* row4 = (const float4*)row;
#pragma unroll 4
    for (int i = 0; i < 31; ++i) {
        float4 v = row4[tid + 256 * i];
        sum += __expf(v.x) + __expf(v.y) + __expf(v.z) + __expf(v.w);
    }
    sum += __expf(row[31744 + tid]);

#pragma unroll
    for (int off = 32; off; off >>= 1) sum += __shfl_down(sum, off);
    __shared__ float red[4];
    __shared__ float s_scale;
    if ((tid & 63) == 0) red[tid >> 6] = sum;
    __syncthreads();
    if (tid == 0) s_scale = (1.0f / ((red[0] + red[1]) + (red[2] + red[3]))) * 0x1p-18f;
    __syncthreads();
    const float scale = s_scale;

#pragma unroll
    for (int k = 0; k < 8; ++k)
        em_lin_T[(size_t)s * (NB * NT) + tid + 256 * k] = __expf(g[k]) * scale;
}

// ---------------------------------------------------------------------------
// K1b: transpose em_lin_T [512][2048] -> em_lin [2048][512]
// ---------------------------------------------------------------------------
__global__ __launch_bounds__(256) void k_tr(
    const float* __restrict__ emT, float* __restrict__ em_lin)
{
    __shared__ float tile[32][33];
    const int jb = blockIdx.x * 32;
    const int sb = blockIdx.y * 32;
    const int cc = threadIdx.x & 31;
    const int rr = threadIdx.x >> 5;
#pragma unroll
    for (int i = 0; i < 4; ++i) {
        int r = rr + 8 * i;
        tile[r][cc] = emT[(size_t)(sb + r) * (NB * NT) + jb + cc];
    }
    __syncthreads();
#pragma unroll
    for (int i = 0; i < 4; ++i) {
        int r = rr + 8 * i;
        em_lin[(size_t)(jb + r) * NS + sb + cc] = tile[cc][r];
    }
}

// ---------------------------------------------------------------------------
// K2a: zscale[k] = 1024 / sum_d exp(tm[k][d])
// ---------------------------------------------------------------------------
__global__ __launch_bounds__(64) void k_z(
    const float* __restrict__ tm, float* __restrict__ zscale)
{
    const int k    = blockIdx.x;
    const int lane = threadIdx.x;
    const float* row = tm + (size_t)k * NS;

    float4 a = ((const float4*)row)[lane * 2];
    float4 b = ((const float4*)row)[lane * 2 + 1];
    float sum = ((__expf(a.x) + __expf(a.y)) + (__expf(a.z) + __expf(a.w)))
              + ((__expf(b.x) + __expf(b.y)) + (__expf(b.z) + __expf(b.w)));
#pragma unroll
    for (int off = 32; off; off >>= 1) sum += __shfl_down(sum, off);
    if (lane == 0) zscale[k] = 1024.0f / sum;
}

// ---------------------------------------------------------------------------
// K2b: PT[d][k] = exp(tm[k][d]) * zscale[k], e4m3 fp8, LDS-transposed tiles.
// ---------------------------------------------------------------------------
__global__ __launch_bounds__(256) void k_pt2(
    const float* __restrict__ tm, const float* __restrict__ zscale,
    unsigned char* __restrict__ PT)
{
    __shared__ float tile[64][65];
    __shared__ float zs[64];
    const int kb  = blockIdx.x * 64;
    const int db  = blockIdx.y * 64;
    const int tid = threadIdx.x;
    const int c   = tid & 63;
    const int r0  = tid >> 6;

    if (tid < 64) zs[tid] = zscale[kb + tid];
#pragma unroll
    for (int i = 0; i < 16; ++i) {
        int r = r0 + 4 * i;
        tile[r][c] = tm[(size_t)(kb + r) * NS + db + c];
    }
    __syncthreads();

    const int d  = tid >> 2;
    const int ks = (tid & 3) * 16;
    unsigned px[4];
#pragma unroll
    for (int gq = 0; gq < 4; ++gq) {
        int k0 = ks + gq * 4;
        px[gq] = pack4_e4m3(__expf(tile[k0 + 0][d]) * zs[k0 + 0],
                            __expf(tile[k0 + 1][d]) * zs[k0 + 1],
                            __expf(tile[k0 + 2][d]) * zs[k0 + 2],
                            __expf(tile[k0 + 3][d]) * zs[k0 + 3]);
    }
    uint4 o; o.x = px[0]; o.y = px[1]; o.z = px[2]; o.w = px[3];
    *(uint4*)(PT + (size_t)(db + d) * NS + kb + ks) = o;
}

// ---------------------------------------------------------------------------
// K3 v5: single-barrier step via PER-WAVE fp8 scaling + per-block MFMA e8m0
// scales.
//   Each wave packs its 64-state alpha block with its OWN local max exponent
//   E_w (DPP row-of-16 reduce only, no cross-wave barrier), publishes E_w as
//   a byte next to the Ew tile.  After ONE barrier, every lane broadcast-reads
//   all 8 exponent dwords (uniform address), computes the per-batch global
//   max M_b per-lane, and feeds the MFMA per-lane A-scale byte
//   s8 = 127 + E_w'(block) - M_b  (e8m0), which makes the accumulation
//   bit-identical to the old global-max scheme (s8==0x7F when E_w'==M_b).
//   Ew + wmE are double-buffered so one barrier also covers the WAR hazard
//   across the +/-1-iteration wave skew.  Barriers/step: 3 -> 1; the
//   serialized tid<4 cross-wave max is gone.
// ---------------------------------------------------------------------------
__global__ __launch_bounds__(512, 2) void k_scan(
    const float* __restrict__ em_lin, const unsigned char* __restrict__ PT,
    const float* __restrict__ p, float* __restrict__ out)
{
    const int bb  = blockIdx.x;        // batch group: global batches bb*4+0..3
    const int tid = threadIdx.x;
    const int w   = tid >> 6;          // wave 0..7
    const int l   = tid & 63;          // lane
    const int lc  = l & 15;            // state-col within 16-tile
    const int lq  = l >> 4;            // local batch 0..3

    __shared__ unsigned Ew[2][16 * 128];           // 16 KB, double-buffered
    __shared__ __align__(16) unsigned char wmE[2][32]; // [buf][w*4+lq] exp bytes
    __shared__ float    wm2[8][4];
    __shared__ float    sbuf[4];

    // ---- load B fragments (P, once) ----
    v8i B[4][4];
#pragma unroll
    for (int nt = 0; nt < 4; ++nt) {
#pragma unroll
        for (int kt = 0; kt < 4; ++kt) {
            const uint4* src = (const uint4*)(PT + (size_t)((w * 4 + nt) * 16 + lc) * NS + kt * 128 + lq * 32);
            uint4 lo = src[0], hi = src[1];
            v8i bb8;
            bb8[0] = (int)lo.x; bb8[1] = (int)lo.y; bb8[2] = (int)lo.z; bb8[3] = (int)lo.w;
            bb8[4] = (int)hi.x; bb8[5] = (int)hi.y; bb8[6] = (int)hi.z; bb8[7] = (int)hi.w;
            B[nt][kt] = bb8;
        }
    }

    // ---- prior softmax denominator ----
    float zp = 0.f;
#pragma unroll
    for (int i = 0; i < 8; ++i) zp += __expf(p[l * 8 + i]);
    DPPADD(zp, 0x128); DPPADD(zp, 0x124); DPPADD(zp, 0xB1); DPPADD(zp, 0x4E);
    float Zp = __int_as_float(__builtin_amdgcn_readlane(__float_as_int(zp), 0))
             + __int_as_float(__builtin_amdgcn_readlane(__float_as_int(zp), 16))
             + __int_as_float(__builtin_amdgcn_readlane(__float_as_int(zp), 32))
             + __int_as_float(__builtin_amdgcn_readlane(__float_as_int(zp), 48));
    const float invZp = 1.0f / Zp;

    const int dbase0 = w * 64 + lc;          // state d for nt: dbase0 + 16*nt
    const int gb     = bb * 4 + lq;          // global batch of this thread

    // ---- alpha_0 (linear; 2^-18 embedded in em_lin -> shift starts at 18) ----
    const float* epb0 = em_lin + (size_t)gb * (NT * NS) + dbase0;
    float alpha[4];
#pragma unroll
    for (int nt = 0; nt < 4; ++nt)
        alpha[nt] = __expf(p[dbase0 + 16 * nt]) * invZp * epb0[16 * nt];

    int gsum = 18;
    const unsigned sel1 = (l & 1) ? 0x07030501u : 0x02060004u;
    const unsigned sel2 = (l & 2) ? 0x07060302u : 0x01000504u;
    const int mrow = 4 * lq + (l & 3);

    // hoisted, t-invariant A-read uint4-indices and Ew write dword-indices
    int aidx[8];
#pragma unroll
    for (int kt = 0; kt < 4; ++kt) {
#pragma unroll
        for (int c = 0; c < 2; ++c)
            aidx[kt * 2 + c] = lc * 32 + (((kt * 8 + lq * 2 + c) ^ lc) & 31);
    }
    int widx[4];
#pragma unroll
    for (int nt = 0; nt < 4; ++nt)
        widx[nt] = mrow * 128 + ((((w * 4 + nt) ^ mrow) & 31) << 2) + (lc >> 2);

    // A-row held by this lane is row lc -> batch bA = lc>>2 (rows % 4 != 0 are
    // zero; their scale value is irrelevant as long as it's not e8m0-NaN).
    const int bA = lc >> 2;
    const int h  = lq >> 1;                 // producer wave w' = 2*kt + h
    const unsigned shA = (unsigned)(bA << 3);
    const unsigned shQ = (unsigned)(lq << 3);

    const float* epb = epb0 + NS;            // emission pointer, stepped by NS

    for (int t = 1; t < NT; ++t) {
        const int buf = t & 1;
        unsigned* EwB = &Ew[buf][0];

        // ---- prefetch em (consumed at end of iteration) ----
        float epf[4];
#pragma unroll
        for (int nt = 0; nt < 4; ++nt) epf[nt] = epb[16 * nt];
        epb += NS;

        // ---- per-batch WAVE-LOCAL max (row of 16 = one batch) ----
        float mx = fmaxf(fmaxf(alpha[0], alpha[1]), fmaxf(alpha[2], alpha[3]));
        DPPMAX(mx, 0x128); DPPMAX(mx, 0x124); DPPMAX(mx, 0xB1); DPPMAX(mx, 0x4E);
        unsigned E = __float_as_uint(mx) >> 23;
        E = E > 1u ? E : 1u;                 // keep sc encodable even if block ~0
        const float sc = __uint_as_float((261u - E) << 23);   // 2^(134-E)

        // ---- e -> fp8 (LOCAL scale), DPP 4x4 byte transpose, Ew write ----
#pragma unroll
        for (int nt = 0; nt < 4; ++nt) {
            unsigned dw = pack4_e4m3(alpha[nt] * sc, 0.f, 0.f, 0.f);
            int tmp = __builtin_amdgcn_mov_dpp((int)dw, 0xB1, 0xF, 0xF, true);
            dw = __builtin_amdgcn_perm(dw, (unsigned)tmp, sel1);
            tmp = __builtin_amdgcn_mov_dpp((int)dw, 0x4E, 0xF, 0xF, true);
            dw = __builtin_amdgcn_perm(dw, (unsigned)tmp, sel2);
            EwB[widx[nt]] = dw;
        }
        if (lc == 0) wmE[buf][w * 4 + lq] = (unsigned char)E;
        __syncthreads();                                    // the ONLY barrier

        // ---- broadcast-read all 8 wave-exponent dwords (uniform address) ----
        const uint4 ua = *(const uint4*)&wmE[buf][0];
        const uint4 ub = *(const uint4*)&wmE[buf][16];
        const unsigned d0 = ua.x, d1 = ua.y, d2 = ua.z, d3 = ua.w;
        const unsigned d4 = ub.x, d5 = ub.y, d6 = ub.z, d7 = ub.w;

        // per-batch bytes for the A-row batch (MFMA scales)
        const unsigned a0 = (d0 >> shA) & 255u, a1 = (d1 >> shA) & 255u;
        const unsigned a2 = (d2 >> shA) & 255u, a3 = (d3 >> shA) & 255u;
        const unsigned a4 = (d4 >> shA) & 255u, a5 = (d5 >> shA) & 255u;
        const unsigned a6 = (d6 >> shA) & 255u, a7 = (d7 >> shA) & 255u;
        const unsigned MA = UMX(UMX(UMX(a0, a1), UMX(a2, a3)),
                                UMX(UMX(a4, a5), UMX(a6, a7)));

        // per-batch bytes for THIS thread's batch (exact gsum bookkeeping)
        const unsigned q0 = (d0 >> shQ) & 255u, q1 = (d1 >> shQ) & 255u;
        const unsigned q2 = (d2 >> shQ) & 255u, q3 = (d3 >> shQ) & 255u;
        const unsigned q4 = (d4 >> shQ) & 255u, q5 = (d5 >> shQ) & 255u;
        const unsigned q6 = (d6 >> shQ) & 255u, q7 = (d7 >> shQ) & 255u;
        const unsigned MQ = UMX(UMX(UMX(q0, q1), UMX(q2, q3)),
                                UMX(UMX(q4, q5), UMX(q6, q7)));
        gsum += (int)MQ - 126;

        // per-kt A-scale bytes: producer wave w' = 2*kt + h, batch bA
        const unsigned e0 = h ? a1 : a0;
        const unsigned e1 = h ? a3 : a2;
        const unsigned e2 = h ? a5 : a4;
        const unsigned e3 = h ? a7 : a6;
        int s0 = (int)e0 + 127 - (int)MA; s0 = s0 < 0 ? 0 : s0;
        int s1 = (int)e1 + 127 - (int)MA; s1 = s1 < 0 ? 0 : s1;
        int s2 = (int)e2 + 127 - (int)MA; s2 = s2 < 0 ? 0 : s2;
        int s3 = (int)e3 + 127 - (int)MA; s3 = s3 < 0 ? 0 : s3;
        const int scA[4] = { s0 * 0x01010101, s1 * 0x01010101,
                             s2 * 0x01010101, s3 * 0x01010101 };

        // ---- A fragments from LDS (hoisted swizzled indices) ----
        v8i A[4];
        const uint4* eb4 = (const uint4*)EwB;
#pragma unroll
        for (int kt = 0; kt < 4; ++kt) {
            uint4 lo = eb4[aidx[kt * 2 + 0]];
            uint4 hi = eb4[aidx[kt * 2 + 1]];
            v8i aa;
            aa[0] = (int)lo.x; aa[1] = (int)lo.y; aa[2] = (int)lo.z; aa[3] = (int)lo.w;
            aa[4] = (int)hi.x; aa[5] = (int)hi.y; aa[6] = (int)hi.z; aa[7] = (int)hi.w;
            A[kt] = aa;
        }

        // ---- MFMA: Y = E . P with per-lane e8m0 A-scales ----
        v4f C[4];
#pragma unroll
        for (int nt = 0; nt < 4; ++nt) { C[nt][0] = 0.f; C[nt][1] = 0.f; C[nt][2] = 0.f; C[nt][3] = 0.f; }
#pragma unroll
        for (int kt = 0; kt < 4; ++kt)
#pragma unroll
            for (int nt = 0; nt < 4; ++nt)
                C[nt] = __builtin_amdgcn_mfma_scale_f32_16x16x128_f8f6f4(
                            A[kt], B[nt][kt], C[nt], 0, 0, 0, scA[kt], 0, 0x7F7F7F7F);

        // ---- alpha update (linear); batch lq = C-row 4*lq = reg 0 ----
#pragma unroll
        for (int nt = 0; nt < 4; ++nt)
            alpha[nt] = C[nt][0] * epf[nt];
    }

    // ---- final: per-batch logsumexp over states ----
    {
        float sm = (alpha[0] + alpha[1]) + (alpha[2] + alpha[3]);
        DPPADD(sm, 0x128); DPPADD(sm, 0x124); DPPADD(sm, 0xB1); DPPADD(sm, 0x4E);
        if (lc == 0) wm2[w][lq] = sm;
        if (w == 0 && lc == 0) sbuf[lq] = (float)gsum;
    }
    __syncthreads();
    if (tid < 4) {
        float s8 = ((wm2[0][tid] + wm2[1][tid]) + (wm2[2][tid] + wm2[3][tid]))
                 + ((wm2[4][tid] + wm2[5][tid]) + (wm2[6][tid] + wm2[7][tid]));
        float L2 = __log2f(s8) + sbuf[tid];
        atomicAdd(out, -(0.693147180559945f / 16.0f) * L2);
    }
}

// ---------------------------------------------------------------------------
extern "C" void kernel_launch(void* const* d_in, const int* in_sizes, int n_in,
                              void* d_out, int out_size, void* d_ws, size_t ws_size,
                              hipStream_t stream)
{
    const int*   ids = (const int*)d_in[0];   // [16][128]
    const float* em  = (const float*)d_in[1]; // [512][32000]
    const float* tm  = (const float*)d_in[2]; // [512][512]
    const float* p   = (const float*)d_in[3]; // [512]
    float* out = (float*)d_out;

    float*          em_lin = (float*)d_ws;
    unsigned char*  PT     = (unsigned char*)d_ws + ((size_t)4 << 20);
    float*          zscale = (float*)((unsigned char*)d_ws + ((size_t)4 << 20) + ((size_t)256 << 10));
    float*          emT    = (float*)((unsigned char*)d_ws + ((size_t)4 << 20) + ((size_t)512 << 10));

    hipMemsetAsync(d_out, 0, sizeof(float), stream);

    k_emtok_T<<<NS, 256, 0, stream>>>(em, ids, emT);
    k_tr<<<dim3(64, 16), 256, 0, stream>>>(emT, em_lin);
    k_z<<<NS, 64, 0, stream>>>(tm, zscale);
    k_pt2<<<dim3(8, 8), 256, 0, stream>>>(tm, zscale, PT);
    k_scan<<<4, 512, 0, stream>>>(em_lin, PT, p, out);
}